// Round 15
// baseline (883.977 us; speedup 1.0000x reference)
//
#include <hip/hip_runtime.h>
#include <math.h>

#define DD 1024
#define TT 2048
#define BB 4
#define HH 4
#define HDIM 256
#define NLAYER 2
#define MM (BB*TT)          // 8192 rows
#define NCHUNK 64
#define CHUNK (TT/NCHUNK)   // 32

typedef unsigned short u16;
typedef __bf16 bf16x8 __attribute__((ext_vector_type(8)));
typedef float f32x4 __attribute__((ext_vector_type(4)));

__device__ __forceinline__ float b2f(u16 h) {
  unsigned u = ((unsigned)h) << 16;
  return __builtin_bit_cast(float, u);
}
__device__ __forceinline__ u16 f2b(float f) {
  unsigned u = __builtin_bit_cast(unsigned, f);
  u += 0x7fffu + ((u >> 16) & 1u);
  return (u16)(u >> 16);
}
__device__ __forceinline__ float blo(unsigned u) { return __builtin_bit_cast(float, u << 16); }
__device__ __forceinline__ float bhi(unsigned u) { return __builtin_bit_cast(float, u & 0xffff0000u); }

#define GLD16(g, l) __builtin_amdgcn_global_load_lds( \
    (__attribute__((address_space(1))) void*)(void*)(g), \
    (__attribute__((address_space(3))) void*)(l), 16, 0, 0)

__device__ __forceinline__ void wg_barrier() {
  asm volatile("" ::: "memory");
  __builtin_amdgcn_s_barrier();
  asm volatile("" ::: "memory");
}
template<int N> __device__ __forceinline__ void wait_vmcnt() {
  asm volatile("s_waitcnt vmcnt(%0)" :: "i"(N) : "memory");
}

// ------- weight fp32 -> bf16 transpose: Wt[N][K] = W[K][N], batched over layers -------
__global__ __launch_bounds__(256)
void transpose_cvt(const float* __restrict__ W, u16* __restrict__ Wt, int K, int N,
                   size_t lsrc, size_t ldst) {
  __shared__ float tile[32][33];
  const float* Wl = W + (size_t)blockIdx.z * lsrc;
  u16* Wtl = Wt + (size_t)blockIdx.z * ldst;
  const int n0 = blockIdx.x << 5, k0 = blockIdx.y << 5;
  const int tx = threadIdx.x, ty = threadIdx.y;
#pragma unroll
  for (int i = 0; i < 4; ++i)
    tile[ty + i*8][tx] = Wl[(size_t)(k0 + ty + i*8) * N + n0 + tx];
  __syncthreads();
#pragma unroll
  for (int i = 0; i < 4; ++i)
    Wtl[(size_t)(n0 + ty + i*8) * K + k0 + tx] = f2b(tile[tx][ty + i*8]);
}

// ---------------- fp32 -> bf16 cast (residual stream init) ----------------
__global__ __launch_bounds__(256)
void cast_k(const float* __restrict__ in, u16* __restrict__ out) {
  const size_t i = ((size_t)blockIdx.x * 256 + threadIdx.x) << 3;
  const float4 a = *(const float4*)(in + i);
  const float4 b = *(const float4*)(in + i + 4);
  uint4 pk;
  pk.x = (unsigned)f2b(a.x) | ((unsigned)f2b(a.y) << 16);
  pk.y = (unsigned)f2b(a.z) | ((unsigned)f2b(a.w) << 16);
  pk.z = (unsigned)f2b(b.x) | ((unsigned)f2b(b.y) << 16);
  pk.w = (unsigned)f2b(b.z) | ((unsigned)f2b(b.w) << 16);
  *(uint4*)(out + i) = pk;
}

// ---------------- LayerNorm: wave-per-row, no LDS/barriers ----------------
// grid MM/4, 256 threads = 4 waves; each wave one row; lane handles 16 elems.
__global__ __launch_bounds__(256)
void ln_k(const u16* __restrict__ xb, const float* __restrict__ sc,
          const float* __restrict__ bi, u16* __restrict__ xn) {
  const int tid = threadIdx.x;
  const int lane = tid & 63;
  const int row = blockIdx.x * 4 + (tid >> 6);
  const int c0 = lane << 4;
  const u16* xr = xb + (size_t)row * DD + c0;
  const uint4 v0 = *(const uint4*)(xr);
  const uint4 v1 = *(const uint4*)(xr + 8);
  float xv[16];
  xv[0]=blo(v0.x); xv[1]=bhi(v0.x); xv[2]=blo(v0.y); xv[3]=bhi(v0.y);
  xv[4]=blo(v0.z); xv[5]=bhi(v0.z); xv[6]=blo(v0.w); xv[7]=bhi(v0.w);
  xv[8]=blo(v1.x); xv[9]=bhi(v1.x); xv[10]=blo(v1.y); xv[11]=bhi(v1.y);
  xv[12]=blo(v1.z); xv[13]=bhi(v1.z); xv[14]=blo(v1.w); xv[15]=bhi(v1.w);
  float s = 0.f, q = 0.f;
#pragma unroll
  for (int e = 0; e < 16; ++e) { s += xv[e]; q += xv[e]*xv[e]; }
#pragma unroll
  for (int o = 1; o < 64; o <<= 1) { s += __shfl_xor(s, o); q += __shfl_xor(q, o); }
  const float mean = s * (1.f / DD);
  const float var = q * (1.f / DD) - mean * mean;
  const float rstd = rsqrtf(var + 1e-5f);
  const float4 s0 = *(const float4*)(sc + c0);
  const float4 s1 = *(const float4*)(sc + c0 + 4);
  const float4 s2 = *(const float4*)(sc + c0 + 8);
  const float4 s3 = *(const float4*)(sc + c0 + 12);
  const float4 b0 = *(const float4*)(bi + c0);
  const float4 b1 = *(const float4*)(bi + c0 + 4);
  const float4 b2 = *(const float4*)(bi + c0 + 8);
  const float4 b3 = *(const float4*)(bi + c0 + 12);
  const float scv[16] = {s0.x,s0.y,s0.z,s0.w, s1.x,s1.y,s1.z,s1.w,
                         s2.x,s2.y,s2.z,s2.w, s3.x,s3.y,s3.z,s3.w};
  const float biv[16] = {b0.x,b0.y,b0.z,b0.w, b1.x,b1.y,b1.z,b1.w,
                         b2.x,b2.y,b2.z,b2.w, b3.x,b3.y,b3.z,b3.w};
  u16 ov[16];
#pragma unroll
  for (int e = 0; e < 16; ++e)
    ov[e] = f2b((xv[e] - mean) * rstd * scv[e] + biv[e]);
  uint4 p0, p1;
  p0.x = (unsigned)ov[0] | ((unsigned)ov[1] << 16);
  p0.y = (unsigned)ov[2] | ((unsigned)ov[3] << 16);
  p0.z = (unsigned)ov[4] | ((unsigned)ov[5] << 16);
  p0.w = (unsigned)ov[6] | ((unsigned)ov[7] << 16);
  p1.x = (unsigned)ov[8] | ((unsigned)ov[9] << 16);
  p1.y = (unsigned)ov[10] | ((unsigned)ov[11] << 16);
  p1.z = (unsigned)ov[12] | ((unsigned)ov[13] << 16);
  p1.w = (unsigned)ov[14] | ((unsigned)ov[15] << 16);
  u16* orow = xn + (size_t)row * DD + c0;
  *(uint4*)(orow) = p0;
  *(uint4*)(orow + 8) = p1;
}

// ======== 256x128 8-wave GEMM, 16x16x32, BK=32, 3-buffer LDS (wide GEMMs) ========
// C[M,N] = A[M,K]*Wt[N,K]^T + bias.  512 threads, 72KB dynamic LDS.
// EPI: 2 = bf16 gelu store, 4 = qkv split (QK rowmajor + V^T), 5 = dual bf16 store
template<int EPI>
__global__ __launch_bounds__(512, 4)
void gemm256t(const u16* __restrict__ A, const u16* __restrict__ Wt,
              const float* __restrict__ bias, const float* __restrict__ bias2,
              float* __restrict__ outf, u16* __restrict__ outb, int K, int N) {
  extern __shared__ u16 lds[];
  const int tid = threadIdx.x;
  const int gx = gridDim.x;
  const int nwg = gx * (int)gridDim.y;
  int lid = (int)blockIdx.y * gx + (int)blockIdx.x;
  lid = (lid & 7) * (nwg >> 3) + (lid >> 3);     // XCD-chunked (nwg % 8 == 0)
  const int m0 = (lid / gx) << 8;
  const int n0 = (lid % gx) << 7;
  const int lane = tid & 63;
  const int wid = tid >> 6;
  const int wm = wid >> 2;
  const int wn = wid & 3;
  const int g = lane >> 4;
  const int lc = lane & 15;
  const int q = tid >> 2;
  const int slot = tid & 3;
  const int scs = (slot ^ ((q >> 1) & 3)) << 3;
  const int so = (g ^ ((lc >> 1) & 3)) << 3;

  u16* Ab = lds;            // 3 x [256][32]
  u16* Bbase = lds + 24576; // 3 x [128][32]
  u16 *Ac = Ab, *An = Ab + 8192, *Aw = Ab + 16384;
  u16 *Bc = Bbase, *Bn = Bbase + 4096, *Bw = Bbase + 8192;

  auto stage = [&](int kt, u16* At, u16* Bt) {
    const int kb = (kt << 5) + scs;
    GLD16(A + (size_t)(m0 + q) * K + kb,       At + q*32 + slot*8);
    GLD16(A + (size_t)(m0 + 128 + q) * K + kb, At + (128 + q)*32 + slot*8);
    GLD16(Wt + (size_t)(n0 + q) * K + kb,      Bt + q*32 + slot*8);
  };

  f32x4 acc[8][2];
#pragma unroll
  for (int i = 0; i < 8; ++i)
#pragma unroll
    for (int j = 0; j < 2; ++j)
#pragma unroll
      for (int e = 0; e < 4; ++e) acc[i][j][e] = 0.f;

  const int KT = K >> 5;
  stage(0, Ac, Bc);
  stage(1, An, Bn);

  for (int kt = 0; kt < KT; ++kt) {
    if (kt + 1 < KT) wait_vmcnt<3>();
    else             wait_vmcnt<0>();
    wg_barrier();
    bf16x8 bf0 = *(const bf16x8*)(Bc + (wn*32 + lc)*32 + so);
    bf16x8 bf1 = *(const bf16x8*)(Bc + (wn*32 + 16 + lc)*32 + so);
    bf16x8 af[8];
#pragma unroll
    for (int i = 0; i < 8; ++i)
      af[i] = *(const bf16x8*)(Ac + (wm*128 + i*16 + lc)*32 + so);
    if (kt + 2 < KT) stage(kt + 2, Aw, Bw);
    __builtin_amdgcn_s_setprio(1);
#pragma unroll
    for (int i = 0; i < 8; ++i) {
      acc[i][0] = __builtin_amdgcn_mfma_f32_16x16x32_bf16(af[i], bf0, acc[i][0], 0, 0, 0);
      acc[i][1] = __builtin_amdgcn_mfma_f32_16x16x32_bf16(af[i], bf1, acc[i][1], 0, 0, 0);
    }
    __builtin_amdgcn_s_setprio(0);
    u16* t;
    t = Ac; Ac = An; An = Aw; Aw = t;
    t = Bc; Bc = Bn; Bn = Bw; Bw = t;
  }

#pragma unroll
  for (int mi = 0; mi < 8; ++mi) {
#pragma unroll
    for (int ni = 0; ni < 2; ++ni) {
      const int n = n0 + wn*32 + ni*16 + lc;
      const int mbase = m0 + wm*128 + mi*16 + (g << 2);
      if (EPI == 4) {
        const float bia = bias[n];
        if (n < 2048) {
#pragma unroll
          for (int e = 0; e < 4; ++e)
            outb[(size_t)(mbase + e) * 2048 + n] = f2b(acc[mi][ni][e] + bia);
        } else {
          const int hh = (n - 2048) >> 8, dim = (n - 2048) & 255;
          const int bidx = mbase >> 11, t = mbase & 2047;
          const u16 a0 = f2b(acc[mi][ni][0] + bia);
          const u16 a1 = f2b(acc[mi][ni][1] + bia);
          const u16 a2 = f2b(acc[mi][ni][2] + bia);
          const u16 a3 = f2b(acc[mi][ni][3] + bia);
          uint2 pk;
          pk.x = (unsigned)a0 | ((unsigned)a1 << 16);
          pk.y = (unsigned)a2 | ((unsigned)a3 << 16);
          u16* vtp = (u16*)outf;
          *(uint2*)(vtp + ((size_t)((bidx*4 + hh)*256 + dim)) * 2048 + t) = pk;
        }
      } else if (EPI == 5) {
        const float bia = (n < 1024) ? bias[n] : bias2[n - 1024];
        u16* dst = (n < 1024) ? outb : (u16*)outf;
        const int nn = n & 1023;
#pragma unroll
        for (int e = 0; e < 4; ++e)
          dst[(size_t)(mbase + e) * 1024 + nn] = f2b(acc[mi][ni][e] + bia);
      } else {  // EPI == 2
        const float bia = bias[n];
#pragma unroll
        for (int e = 0; e < 4; ++e) {
          const float v = acc[mi][ni][e] + bia;
          const float zc = fminf(fmaxf(1.5957691216f * (v + 0.044715f*v*v*v), -30.f), 30.f);
          outb[(size_t)(mbase + e) * N + n] = f2b(v / (1.f + __expf(-zc)));
        }
      }
    }
  }
}

// ======== 128x128 4-wave GEMM (N=1024 residual GEMMs), bf16 residual stream ========
// out = addb(bf16) + A*Wt^T + bias.  FINAL=0: write bf16 xb; FINAL=1: write fp32 d_out.
template<int FINAL>
__global__ __launch_bounds__(256, 2)
void gemm128t(const u16* __restrict__ A, const u16* __restrict__ Wt,
              const float* __restrict__ bias, const u16* __restrict__ addb,
              float* __restrict__ outf, u16* __restrict__ outxb, int K, int N) {
  extern __shared__ u16 lds[];
  const int tid = threadIdx.x;
  const int gx = gridDim.x;  // 8
  const int nwg = gx * (int)gridDim.y;
  int lid = (int)blockIdx.y * gx + (int)blockIdx.x;
  lid = (lid & 7) * (nwg >> 3) + (lid >> 3);
  const int m0 = (lid / gx) << 7;
  const int n0 = (lid % gx) << 7;
  const int lane = tid & 63;
  const int wid = tid >> 6;
  const int wm = wid >> 1;
  const int wn = wid & 1;
  const int g = lane >> 4;
  const int lc = lane & 15;
  const int q = tid >> 2;
  const int slot = tid & 3;
  const int scs = (slot ^ ((q >> 1) & 3)) << 3;
  const int so = (g ^ ((lc >> 1) & 3)) << 3;

  u16* Ab = lds;            // 3 x [128][32]
  u16* Bbase = lds + 12288; // 3 x [128][32]
  u16 *Ac = Ab, *An = Ab + 4096, *Aw = Ab + 8192;
  u16 *Bc = Bbase, *Bn = Bbase + 4096, *Bw = Bbase + 8192;

  auto stage = [&](int kt, u16* At, u16* Bt) {
    const int kb = (kt << 5) + scs;
    GLD16(A + (size_t)(m0 + q) * K + kb,       At + q*32 + slot*8);
    GLD16(A + (size_t)(m0 + 64 + q) * K + kb,  At + (64 + q)*32 + slot*8);
    GLD16(Wt + (size_t)(n0 + q) * K + kb,      Bt + q*32 + slot*8);
    GLD16(Wt + (size_t)(n0 + 64 + q) * K + kb, Bt + (64 + q)*32 + slot*8);
  };

  f32x4 acc[4][4];
#pragma unroll
  for (int i = 0; i < 4; ++i)
#pragma unroll
    for (int j = 0; j < 4; ++j)
#pragma unroll
      for (int e = 0; e < 4; ++e) acc[i][j][e] = 0.f;

  const int KT = K >> 5;
  stage(0, Ac, Bc);
  stage(1, An, Bn);

  for (int kt = 0; kt < KT; ++kt) {
    if (kt + 1 < KT) wait_vmcnt<4>();
    else             wait_vmcnt<0>();
    wg_barrier();
    bf16x8 af[4], bfr[4];
#pragma unroll
    for (int i = 0; i < 4; ++i)
      af[i] = *(const bf16x8*)(Ac + (wm*64 + i*16 + lc)*32 + so);
#pragma unroll
    for (int j = 0; j < 4; ++j)
      bfr[j] = *(const bf16x8*)(Bc + (wn*64 + j*16 + lc)*32 + so);
    if (kt + 2 < KT) stage(kt + 2, Aw, Bw);
    __builtin_amdgcn_s_setprio(1);
#pragma unroll
    for (int i = 0; i < 4; ++i)
#pragma unroll
      for (int j = 0; j < 4; ++j)
        acc[i][j] = __builtin_amdgcn_mfma_f32_16x16x32_bf16(af[i], bfr[j], acc[i][j], 0, 0, 0);
    __builtin_amdgcn_s_setprio(0);
    u16* t;
    t = Ac; Ac = An; An = Aw; Aw = t;
    t = Bc; Bc = Bn; Bn = Bw; Bw = t;
  }

#pragma unroll
  for (int mi = 0; mi < 4; ++mi) {
#pragma unroll
    for (int ni = 0; ni < 4; ++ni) {
      const int n = n0 + wn*64 + ni*16 + lc;
      const int mbase = m0 + wm*64 + mi*16 + (g << 2);
      const float bia = bias[n];
#pragma unroll
      for (int e = 0; e < 4; ++e) {
        const size_t idx = (size_t)(mbase + e) * N + n;
        const float v = b2f(addb[idx]) + acc[mi][ni][e] + bia;
        if (FINAL) outf[idx] = v;
        else       outxb[idx] = f2b(v);
      }
    }
  }
}

// ------- RG-LRU chunked scan, vectorized 8 dims/thread (bf16 z,u) -------
// h_t = g*h_{t-1} + (1-g)*u.  CHUNK=32, NCHUNK=64.
__device__ __forceinline__ void unpack8(uint4 v, float* o) {
  o[0]=blo(v.x); o[1]=bhi(v.x); o[2]=blo(v.y); o[3]=bhi(v.y);
  o[4]=blo(v.z); o[5]=bhi(v.z); o[6]=blo(v.w); o[7]=bhi(v.w);
}

__global__ __launch_bounds__(128)
void scan1_k(const u16* __restrict__ zpre, const u16* __restrict__ u,
             float* __restrict__ aggA, float* __restrict__ aggB) {
  const int d8 = threadIdx.x << 3;
  const int c = blockIdx.x, b = blockIdx.y;
  const size_t base = ((size_t)b * TT + (size_t)c * CHUNK) * DD + d8;
  float a[8], acc[8];
#pragma unroll
  for (int e = 0; e < 8; ++e) { a[e] = 1.f; acc[e] = 0.f; }
  for (int t = 0; t < CHUNK; ++t) {
    float zv[8], uv[8];
    unpack8(*(const uint4*)(zpre + base + (size_t)t * DD), zv);
    unpack8(*(const uint4*)(u + base + (size_t)t * DD), uv);
#pragma unroll
    for (int e = 0; e < 8; ++e) {
      const float gl = 1.f / (1.f + __expf(-zv[e]));
      acc[e] = gl * acc[e] + (1.f - gl) * uv[e];
      a[e] *= gl;
    }
  }
  const size_t o = ((size_t)b * NCHUNK + c) * DD + d8;
#pragma unroll
  for (int e = 0; e < 8; ++e) { aggA[o + e] = a[e]; aggB[o + e] = acc[e]; }
}

__global__ __launch_bounds__(256)
void scan2_k(const float* __restrict__ aggA, const float* __restrict__ aggB,
             float* __restrict__ carry) {
  const int idx = blockIdx.x * 256 + threadIdx.x;  // b*DD + d
  const int b = idx >> 10, d = idx & 1023;
  float h = 0.f;
  for (int c = 0; c < NCHUNK; ++c) {
    const size_t o = ((size_t)b * NCHUNK + c) * DD + d;
    carry[o] = h;
    h = aggA[o] * h + aggB[o];
  }
}

__global__ __launch_bounds__(128)
void scan3_k(const u16* __restrict__ zpre, const u16* __restrict__ u,
             const float* __restrict__ carry, u16* __restrict__ hout) {
  const int d8 = threadIdx.x << 3;
  const int c = blockIdx.x, b = blockIdx.y;
  const size_t base = ((size_t)b * TT + (size_t)c * CHUNK) * DD + d8;
  const size_t o = ((size_t)b * NCHUNK + c) * DD + d8;
  float h[8];
#pragma unroll
  for (int e = 0; e < 8; ++e) h[e] = carry[o + e];
  for (int t = 0; t < CHUNK; ++t) {
    float zv[8], uv[8];
    unpack8(*(const uint4*)(zpre + base + (size_t)t * DD), zv);
    unpack8(*(const uint4*)(u + base + (size_t)t * DD), uv);
    uint4 pk;
    unsigned w[8];
#pragma unroll
    for (int e = 0; e < 8; ++e) {
      const float gl = 1.f / (1.f + __expf(-zv[e]));
      h[e] = gl * h[e] + (1.f - gl) * uv[e];
      w[e] = (unsigned)f2b(h[e]);
    }
    pk.x = w[0] | (w[1] << 16);
    pk.y = w[2] | (w[3] << 16);
    pk.z = w[4] | (w[5] << 16);
    pk.w = w[6] | (w[7] << 16);
    *(uint4*)(hout + base + (size_t)t * DD) = pk;
  }
}

// ---------------- MFMA local-window attention ----------------
__global__ __launch_bounds__(256)
void attn_mfma(const u16* __restrict__ qkb, const u16* __restrict__ vt,
               u16* __restrict__ y) {
  __shared__ u16 kv[16384];
  __shared__ u16 pb[4][16][200];
  const int tid = threadIdx.x;
  const int lane = tid & 63;
  const int wid = tid >> 6;
  const int g = lane >> 4;
  const int lc = lane & 15;
  const int t0 = blockIdx.x << 6;
  const int bh = blockIdx.y;
  const int bT = (bh >> 2) * TT;
  const int h = bh & 3;

  bf16x8 afq[8];
  {
    const u16* qg = qkb + (size_t)(bT + t0 + wid*16 + lc) * 2048 + h*256 + g*8;
#pragma unroll
    for (int ks = 0; ks < 8; ++ks)
      afq[ks] = __builtin_bit_cast(bf16x8, *(const uint4*)(qg + ks*32));
  }

  f32x4 sc[12];
#pragma unroll
  for (int f = 0; f < 12; ++f)
#pragma unroll
    for (int e = 0; e < 4; ++e) sc[f][e] = 0.f;

  const int koff = 1024 + h*256;
#pragma unroll
  for (int c = 0; c < 3; ++c) {
    const int j0 = t0 + (c - 2) * 64;
    if (j0 < 0) {
#pragma unroll
      for (int nt = 0; nt < 4; ++nt)
#pragma unroll
        for (int e = 0; e < 4; ++e) sc[c*4+nt][e] = -1e30f;
      continue;
    }
    __syncthreads();
    {
      const u16* kg = qkb + (size_t)(bT + j0) * 2048 + koff;
#pragma unroll
      for (int i = 0; i < 8; ++i) {
        const int o16 = i*256 + tid;
        const int slab = o16 >> 8, key = (o16 >> 2) & 63, ds = o16 & 3;
        GLD16(kg + (size_t)key*2048 + slab*32 + ds*8, kv + o16*8);
      }
    }
    __syncthreads();
#pragma unroll
    for (int nt = 0; nt < 4; ++nt) {
      f32x4 s = sc[c*4+nt];
#pragma unroll
      for (int ks = 0; ks < 8; ++ks) {
        const bf16x8 kb = *(const bf16x8*)(kv + ks*2048 + (nt*16 + lc)*32 + g*8);
        s = __builtin_amdgcn_mfma_f32_16x16x32_bf16(afq[ks], kb, s, 0, 0, 0);
      }
      sc[c*4+nt] = s;
    }
#pragma unroll
    for (int nt = 0; nt < 4; ++nt)
#pragma unroll
      for (int e = 0; e < 4; ++e) {
        const int tl = wid*16 + g*4 + e;
        const int jl = nt*16 + lc;
        const bool ok = (c == 1) || (c == 2 ? (jl <= tl) : (jl >= tl + 1));
        sc[c*4+nt][e] = ok ? sc[c*4+nt][e] * 0.0625f : -1e30f;
      }
  }

#pragma unroll
  for (int e = 0; e < 4; ++e) {
    float m = -1e30f;
#pragma unroll
    for (int f = 0; f < 12; ++f) m = fmaxf(m, sc[f][e]);
    m = fmaxf(m, __shfl_xor(m, 1)); m = fmaxf(m, __shfl_xor(m, 2));
    m = fmaxf(m, __shfl_xor(m, 4)); m = fmaxf(m, __shfl_xor(m, 8));
    float s = 0.f;
#pragma unroll
    for (int f = 0; f < 12; ++f) { const float p = __expf(sc[f][e] - m); sc[f][e] = p; s += p; }
    s += __shfl_xor(s, 1); s += __shfl_xor(s, 2);
    s += __shfl_xor(s, 4); s += __shfl_xor(s, 8);
    const float is = 1.f / s;
#pragma unroll
    for (int f = 0; f < 12; ++f) sc[f][e] *= is;
  }
#pragma unroll
  for (int c = 0; c < 3; ++c)
#pragma unroll
    for (int nt = 0; nt < 4; ++nt)
#pragma unroll
      for (int e = 0; e < 4; ++e)
        pb[wid][g*4 + e][c*64 + nt*16 + lc] = f2b(sc[c*4+nt][e]);

  f32x4 acc[16];
#pragma unroll
  for (int nt = 0; nt < 16; ++nt)
#pragma unroll
    for (int e = 0; e < 4; ++e) acc[nt][e] = 0.f;

  const u16* vg = vt + (size_t)bh * 256 * 2048;
#pragma unroll
  for (int c = 0; c < 3; ++c) {
    const int j0 = t0 + (c - 2) * 64;
    if (j0 < 0) continue;
    __syncthreads();
#pragma unroll
    for (int i = 0; i < 8; ++i) {
      const int o16 = i*256 + tid;
      const int dim = o16 >> 3, slot = o16 & 7;
      const int ss = slot ^ (dim & 7);
      GLD16(vg + (size_t)dim*2048 + j0 + ss*8, kv + o16*8);
    }
    __syncthreads();
#pragma unroll
    for (int ks = 0; ks < 2; ++ks) {
      const bf16x8 pa = *(const bf16x8*)&pb[wid][lc][(c*2 + ks)*32 + g*8];
#pragma unroll
      for (int nt = 0; nt < 16; ++nt) {
        const int dim = nt*16 + lc;
        int boff = dim*128 + ks*64 + g*16;
        boff ^= (dim & 7) << 4;
        const bf16x8 vb = *(const bf16x8*)((const char*)kv + boff);
        acc[nt] = __builtin_amdgcn_mfma_f32_16x16x32_bf16(pa, vb, acc[nt], 0, 0, 0);
      }
    }
  }

#pragma unroll
  for (int nt = 0; nt < 16; ++nt)
#pragma unroll
    for (int e = 0; e < 4; ++e) {
      const int tok = bT + t0 + wid*16 + g*4 + e;
      y[(size_t)tok * 1024 + h*256 + nt*16 + lc] = f2b(acc[nt][e]);
    }
}

// ---------------- host orchestration ----------------
extern "C" void kernel_launch(void* const* d_in, const int* in_sizes, int n_in,
                              void* d_out, int out_size, void* d_ws, size_t ws_size,
                              hipStream_t stream) {
  const float* x_in      = (const float*)d_in[0];
  const float* ln1_s     = (const float*)d_in[1];
  const float* ln1_b     = (const float*)d_in[2];
  const float* ln2_s     = (const float*)d_in[3];
  const float* ln2_b     = (const float*)d_in[4];
  const float* ln3_s     = (const float*)d_in[5];
  const float* ln3_b     = (const float*)d_in[6];
  const float* rg_in_w   = (const float*)d_in[7];
  const float* rg_in_b   = (const float*)d_in[8];
  const float* rg_gate_w = (const float*)d_in[9];
  const float* rg_gate_b = (const float*)d_in[10];
  const float* rg_out_w  = (const float*)d_in[11];
  const float* rg_out_b  = (const float*)d_in[12];
  const float* qkv_w     = (const float*)d_in[13];
  const float* qkv_b     = (const float*)d_in[14];
  const float* attn_out_w= (const float*)d_in[15];
  const float* attn_out_b= (const float*)d_in[16];
  const float* mlp_w1    = (const float*)d_in[17];
  const float* mlp_b1    = (const float*)d_in[18];
  const float* mlp_w2    = (const float*)d_in[19];
  const float* mlp_b2    = (const float*)d_in[20];

  hipFuncSetAttribute((const void*)&gemm256t<2>, hipFuncAttributeMaxDynamicSharedMemorySize, 73728);
  hipFuncSetAttribute((const void*)&gemm256t<4>, hipFuncAttributeMaxDynamicSharedMemorySize, 73728);
  hipFuncSetAttribute((const void*)&gemm256t<5>, hipFuncAttributeMaxDynamicSharedMemorySize, 73728);
  hipFuncSetAttribute((const void*)&gemm128t<0>, hipFuncAttributeMaxDynamicSharedMemorySize, 49152);
  hipFuncSetAttribute((const void*)&gemm128t<1>, hipFuncAttributeMaxDynamicSharedMemorySize, 49152);

  float* xout = (float*)d_out;
  char* ws = (char*)d_ws;
  u16*  wt     = (u16*)ws;                          // 62,914,560 B (bf16 transposed weights)
  u16*  xn     = (u16*)(ws + 62914560);             // 16,777,216 B
  char* bigS   = ws + 62914560 + 16777216;          // 67,108,864 B
  char* smallS = bigS + 67108864;                   // 16,777,216 B
  float* aggA  = (float*)(smallS + 16777216);       // 1 MB each (B*64*DD floats)
  float* aggB  = aggA + (size_t)BB * NCHUNK * DD;
  float* carry = aggB + (size_t)BB * NCHUNK * DD;
  u16*  xb     = (u16*)(carry + (size_t)BB * NCHUNK * DD);  // 16,777,216 B bf16 residual

  u16* ubuf = (u16*)bigS;                           // RG phase (bf16)
  u16* zbuf = (u16*)(bigS + 33554432);              // pre-sigmoid gate, bf16
  u16* qkb  = (u16*)bigS;                           // attn phase: [8192][2048] QK
  u16* vtb  = (u16*)(bigS + 33554432);              // attn phase: V transposed, 16MB
  u16* hid  = (u16*)bigS;                           // MLP phase
  u16* hbuf = (u16*)smallS;
  u16* ybuf = (u16*)smallS;

  const size_t LW = 15728640;
  const dim3 tb(32, 8);
  // batched over both layers via blockIdx.z
  transpose_cvt<<<dim3(32, 32, 2),  tb, 0, stream>>>(rg_in_w,    wt + 0,        DD, DD,   DD*DD,   LW);
  transpose_cvt<<<dim3(32, 32, 2),  tb, 0, stream>>>(rg_gate_w,  wt + 1048576,  DD, DD,   DD*DD,   LW);
  transpose_cvt<<<dim3(32, 32, 2),  tb, 0, stream>>>(rg_out_w,   wt + 2097152,  DD, DD,   DD*DD,   LW);
  transpose_cvt<<<dim3(96, 32, 2),  tb, 0, stream>>>(qkv_w,      wt + 3145728,  DD, 3072, DD*3072, LW);
  transpose_cvt<<<dim3(32, 32, 2),  tb, 0, stream>>>(attn_out_w, wt + 6291456,  DD, DD,   DD*DD,   LW);
  transpose_cvt<<<dim3(128, 32, 2), tb, 0, stream>>>(mlp_w1,     wt + 7340032,  DD, 4096, DD*4096, LW);
  transpose_cvt<<<dim3(32, 128, 2), tb, 0, stream>>>(mlp_w2,     wt + 11534336, 4096, DD, 4096*DD, LW);
  cast_k<<<4096, 256, 0, stream>>>(x_in, xb);

  for (int l = 0; l < NLAYER; ++l) {
    u16* base = wt + (size_t)l * LW;
    // ---- RG-LRU block (rg_in + rg_gate fused; u and pre-sigmoid z stored bf16)
    ln_k<<<MM/4, 256, 0, stream>>>(xb, ln1_s + l*DD, ln1_b + l*DD, xn);
    gemm256t<5><<<dim3(16, 32), 512, 73728, stream>>>(xn, base + 0, rg_in_b + l*DD, rg_gate_b + l*DD,
                                                      (float*)zbuf, ubuf, DD, 2048);
    scan1_k<<<dim3(NCHUNK, BB), 128, 0, stream>>>(zbuf, ubuf, aggA, aggB);
    scan2_k<<<16, 256, 0, stream>>>(aggA, aggB, carry);
    scan3_k<<<dim3(NCHUNK, BB), 128, 0, stream>>>(zbuf, ubuf, carry, hbuf);
    gemm128t<0><<<dim3(8, 64), 256, 49152, stream>>>(hbuf, base + 2097152, rg_out_b + l*DD,
                                                     xb, nullptr, xb, DD, 1024);
    // ---- local attention block
    ln_k<<<MM/4, 256, 0, stream>>>(xb, ln2_s + l*DD, ln2_b + l*DD, xn);
    gemm256t<4><<<dim3(24, 32), 512, 73728, stream>>>(xn, base + 3145728, qkv_b + l*3072, nullptr,
                                                      (float*)vtb, qkb, DD, 3072);
    attn_mfma<<<dim3(TT/64, BB*HH), 256, 0, stream>>>(qkb, vtb, ybuf);
    gemm128t<0><<<dim3(8, 64), 256, 49152, stream>>>(ybuf, base + 6291456, attn_out_b + l*DD,
                                                     xb, nullptr, xb, DD, 1024);
    // ---- MLP block
    ln_k<<<MM/4, 256, 0, stream>>>(xb, ln3_s + l*DD, ln3_b + l*DD, xn);
    gemm256t<2><<<dim3(32, 32), 512, 73728, stream>>>(xn, base + 7340032, mlp_b1 + l*4096, nullptr,
                                                      nullptr, hid, DD, 4096);
    if (l == NLAYER - 1)
      gemm128t<1><<<dim3(8, 64), 256, 49152, stream>>>(hid, base + 11534336, mlp_b2 + l*DD,
                                                       xb, xout, nullptr, 4096, 1024);
    else
      gemm128t<0><<<dim3(8, 64), 256, 49152, stream>>>(hid, base + 11534336, mlp_b2 + l*DD,
                                                       xb, nullptr, xb, 4096, 1024);
  }
}

// Round 16
// 838.137 us; speedup vs baseline: 1.0547x; 1.0547x over previous
//
#include <hip/hip_runtime.h>
#include <math.h>

#define DD 1024
#define TT 2048
#define BB 4
#define HH 4
#define HDIM 256
#define NLAYER 2
#define MM (BB*TT)          // 8192 rows
#define NCHUNK 32
#define CHUNK (TT/NCHUNK)   // 64

typedef unsigned short u16;
typedef __bf16 bf16x8 __attribute__((ext_vector_type(8)));
typedef float f32x4 __attribute__((ext_vector_type(4)));

__device__ __forceinline__ float b2f(u16 h) {
  unsigned u = ((unsigned)h) << 16;
  return __builtin_bit_cast(float, u);
}
__device__ __forceinline__ u16 f2b(float f) {
  unsigned u = __builtin_bit_cast(unsigned, f);
  u += 0x7fffu + ((u >> 16) & 1u);
  return (u16)(u >> 16);
}
__device__ __forceinline__ float blo(unsigned u) { return __builtin_bit_cast(float, u << 16); }
__device__ __forceinline__ float bhi(unsigned u) { return __builtin_bit_cast(float, u & 0xffff0000u); }

#define GLD16(g, l) __builtin_amdgcn_global_load_lds( \
    (__attribute__((address_space(1))) void*)(void*)(g), \
    (__attribute__((address_space(3))) void*)(l), 16, 0, 0)

__device__ __forceinline__ void wg_barrier() {
  asm volatile("" ::: "memory");
  __builtin_amdgcn_s_barrier();
  asm volatile("" ::: "memory");
}
template<int N> __device__ __forceinline__ void wait_vmcnt() {
  asm volatile("s_waitcnt vmcnt(%0)" :: "i"(N) : "memory");
}

// ------- weight fp32 -> bf16 transpose: Wt[N][K] = W[K][N], batched over layers -------
__global__ __launch_bounds__(256)
void transpose_cvt(const float* __restrict__ W, u16* __restrict__ Wt, int K, int N,
                   size_t lsrc, size_t ldst) {
  __shared__ float tile[32][33];
  const float* Wl = W + (size_t)blockIdx.z * lsrc;
  u16* Wtl = Wt + (size_t)blockIdx.z * ldst;
  const int n0 = blockIdx.x << 5, k0 = blockIdx.y << 5;
  const int tx = threadIdx.x, ty = threadIdx.y;
#pragma unroll
  for (int i = 0; i < 4; ++i)
    tile[ty + i*8][tx] = Wl[(size_t)(k0 + ty + i*8) * N + n0 + tx];
  __syncthreads();
#pragma unroll
  for (int i = 0; i < 4; ++i)
    Wtl[(size_t)(n0 + ty + i*8) * K + k0 + tx] = f2b(tile[tx][ty + i*8]);
}

// ---------------- fp32 -> bf16 cast (residual stream init) ----------------
__global__ __launch_bounds__(256)
void cast_k(const float* __restrict__ in, u16* __restrict__ out) {
  const size_t i = ((size_t)blockIdx.x * 256 + threadIdx.x) << 3;
  const float4 a = *(const float4*)(in + i);
  const float4 b = *(const float4*)(in + i + 4);
  uint4 pk;
  pk.x = (unsigned)f2b(a.x) | ((unsigned)f2b(a.y) << 16);
  pk.y = (unsigned)f2b(a.z) | ((unsigned)f2b(a.w) << 16);
  pk.z = (unsigned)f2b(b.x) | ((unsigned)f2b(b.y) << 16);
  pk.w = (unsigned)f2b(b.z) | ((unsigned)f2b(b.w) << 16);
  *(uint4*)(out + i) = pk;
}

// ---------------- LayerNorm (bf16 residual in, bf16 out) ----------------
__global__ __launch_bounds__(256)
void ln_k(const u16* __restrict__ xb, const float* __restrict__ sc,
          const float* __restrict__ bi, u16* __restrict__ xn) {
  const int row = blockIdx.x;
  const int tid = threadIdx.x;
  const uint2 rv = ((const uint2*)(xb + (size_t)row * DD))[tid];
  const float x0 = blo(rv.x), x1 = bhi(rv.x), x2 = blo(rv.y), x3 = bhi(rv.y);
  float s = x0 + x1 + x2 + x3;
  float q = x0*x0 + x1*x1 + x2*x2 + x3*x3;
#pragma unroll
  for (int o = 1; o < 64; o <<= 1) { s += __shfl_xor(s, o); q += __shfl_xor(q, o); }
  __shared__ float rs[4], rq[4];
  if ((tid & 63) == 0) { rs[tid >> 6] = s; rq[tid >> 6] = q; }
  __syncthreads();
  s = rs[0] + rs[1] + rs[2] + rs[3];
  q = rq[0] + rq[1] + rq[2] + rq[3];
  const float mean = s * (1.f / DD);
  const float var = q * (1.f / DD) - mean * mean;
  const float rstd = rsqrtf(var + 1e-5f);
  const float4 sv = ((const float4*)sc)[tid];
  const float4 bv = ((const float4*)bi)[tid];
  const u16 o0 = f2b((x0 - mean) * rstd * sv.x + bv.x);
  const u16 o1 = f2b((x1 - mean) * rstd * sv.y + bv.y);
  const u16 o2 = f2b((x2 - mean) * rstd * sv.z + bv.z);
  const u16 o3 = f2b((x3 - mean) * rstd * sv.w + bv.w);
  uint2 pk;
  pk.x = (unsigned)o0 | ((unsigned)o1 << 16);
  pk.y = (unsigned)o2 | ((unsigned)o3 << 16);
  *(uint2*)(xn + (size_t)row * DD + (tid << 2)) = pk;
}

// ======== 256x128 8-wave GEMM, 16x16x32, BK=32, 3-buffer LDS (wide GEMMs) ========
// C[M,N] = A[M,K]*Wt[N,K]^T + bias.  512 threads, 72KB dynamic LDS.
// EPI: 2 = bf16 gelu store, 4 = qkv split (QK rowmajor + V^T), 5 = dual bf16 store
template<int EPI>
__global__ __launch_bounds__(512, 4)
void gemm256t(const u16* __restrict__ A, const u16* __restrict__ Wt,
              const float* __restrict__ bias, const float* __restrict__ bias2,
              float* __restrict__ outf, u16* __restrict__ outb, int K, int N) {
  extern __shared__ u16 lds[];
  const int tid = threadIdx.x;
  const int gx = gridDim.x;
  const int nwg = gx * (int)gridDim.y;
  int lid = (int)blockIdx.y * gx + (int)blockIdx.x;
  lid = (lid & 7) * (nwg >> 3) + (lid >> 3);     // XCD-chunked (nwg % 8 == 0)
  const int m0 = (lid / gx) << 8;
  const int n0 = (lid % gx) << 7;
  const int lane = tid & 63;
  const int wid = tid >> 6;
  const int wm = wid >> 2;
  const int wn = wid & 3;
  const int g = lane >> 4;
  const int lc = lane & 15;
  const int q = tid >> 2;
  const int slot = tid & 3;
  const int scs = (slot ^ ((q >> 1) & 3)) << 3;
  const int so = (g ^ ((lc >> 1) & 3)) << 3;

  u16* Ab = lds;            // 3 x [256][32]
  u16* Bbase = lds + 24576; // 3 x [128][32]
  u16 *Ac = Ab, *An = Ab + 8192, *Aw = Ab + 16384;
  u16 *Bc = Bbase, *Bn = Bbase + 4096, *Bw = Bbase + 8192;

  auto stage = [&](int kt, u16* At, u16* Bt) {
    const int kb = (kt << 5) + scs;
    GLD16(A + (size_t)(m0 + q) * K + kb,       At + q*32 + slot*8);
    GLD16(A + (size_t)(m0 + 128 + q) * K + kb, At + (128 + q)*32 + slot*8);
    GLD16(Wt + (size_t)(n0 + q) * K + kb,      Bt + q*32 + slot*8);
  };

  f32x4 acc[8][2];
#pragma unroll
  for (int i = 0; i < 8; ++i)
#pragma unroll
    for (int j = 0; j < 2; ++j)
#pragma unroll
      for (int e = 0; e < 4; ++e) acc[i][j][e] = 0.f;

  const int KT = K >> 5;
  stage(0, Ac, Bc);
  stage(1, An, Bn);

  for (int kt = 0; kt < KT; ++kt) {
    if (kt + 1 < KT) wait_vmcnt<3>();
    else             wait_vmcnt<0>();
    wg_barrier();
    bf16x8 bf0 = *(const bf16x8*)(Bc + (wn*32 + lc)*32 + so);
    bf16x8 bf1 = *(const bf16x8*)(Bc + (wn*32 + 16 + lc)*32 + so);
    bf16x8 af[8];
#pragma unroll
    for (int i = 0; i < 8; ++i)
      af[i] = *(const bf16x8*)(Ac + (wm*128 + i*16 + lc)*32 + so);
    if (kt + 2 < KT) stage(kt + 2, Aw, Bw);
    __builtin_amdgcn_s_setprio(1);
#pragma unroll
    for (int i = 0; i < 8; ++i) {
      acc[i][0] = __builtin_amdgcn_mfma_f32_16x16x32_bf16(af[i], bf0, acc[i][0], 0, 0, 0);
      acc[i][1] = __builtin_amdgcn_mfma_f32_16x16x32_bf16(af[i], bf1, acc[i][1], 0, 0, 0);
    }
    __builtin_amdgcn_s_setprio(0);
    u16* t;
    t = Ac; Ac = An; An = Aw; Aw = t;
    t = Bc; Bc = Bn; Bn = Bw; Bw = t;
  }

#pragma unroll
  for (int mi = 0; mi < 8; ++mi) {
#pragma unroll
    for (int ni = 0; ni < 2; ++ni) {
      const int n = n0 + wn*32 + ni*16 + lc;
      const int mbase = m0 + wm*128 + mi*16 + (g << 2);
      if (EPI == 4) {
        const float bia = bias[n];
        if (n < 2048) {
#pragma unroll
          for (int e = 0; e < 4; ++e)
            outb[(size_t)(mbase + e) * 2048 + n] = f2b(acc[mi][ni][e] + bia);
        } else {
          const int hh = (n - 2048) >> 8, dim = (n - 2048) & 255;
          const int bidx = mbase >> 11, t = mbase & 2047;
          const u16 a0 = f2b(acc[mi][ni][0] + bia);
          const u16 a1 = f2b(acc[mi][ni][1] + bia);
          const u16 a2 = f2b(acc[mi][ni][2] + bia);
          const u16 a3 = f2b(acc[mi][ni][3] + bia);
          uint2 pk;
          pk.x = (unsigned)a0 | ((unsigned)a1 << 16);
          pk.y = (unsigned)a2 | ((unsigned)a3 << 16);
          u16* vtp = (u16*)outf;
          *(uint2*)(vtp + ((size_t)((bidx*4 + hh)*256 + dim)) * 2048 + t) = pk;
        }
      } else if (EPI == 5) {
        const float bia = (n < 1024) ? bias[n] : bias2[n - 1024];
        u16* dst = (n < 1024) ? outb : (u16*)outf;
        const int nn = n & 1023;
#pragma unroll
        for (int e = 0; e < 4; ++e)
          dst[(size_t)(mbase + e) * 1024 + nn] = f2b(acc[mi][ni][e] + bia);
      } else {  // EPI == 2
        const float bia = bias[n];
#pragma unroll
        for (int e = 0; e < 4; ++e) {
          const float v = acc[mi][ni][e] + bia;
          const float zc = fminf(fmaxf(1.5957691216f * (v + 0.044715f*v*v*v), -30.f), 30.f);
          outb[(size_t)(mbase + e) * N + n] = f2b(v / (1.f + __expf(-zc)));
        }
      }
    }
  }
}

// ======== 128x128 4-wave GEMM (N=1024 residual GEMMs), bf16 residual stream ========
// out = addb(bf16) + A*Wt^T + bias.  FINAL=0: write bf16 xb; FINAL=1: write fp32 d_out.
template<int FINAL>
__global__ __launch_bounds__(256, 2)
void gemm128t(const u16* __restrict__ A, const u16* __restrict__ Wt,
              const float* __restrict__ bias, const u16* __restrict__ addb,
              float* __restrict__ outf, u16* __restrict__ outxb, int K, int N) {
  extern __shared__ u16 lds[];
  const int tid = threadIdx.x;
  const int gx = gridDim.x;  // 8
  const int nwg = gx * (int)gridDim.y;
  int lid = (int)blockIdx.y * gx + (int)blockIdx.x;
  lid = (lid & 7) * (nwg >> 3) + (lid >> 3);
  const int m0 = (lid / gx) << 7;
  const int n0 = (lid % gx) << 7;
  const int lane = tid & 63;
  const int wid = tid >> 6;
  const int wm = wid >> 1;
  const int wn = wid & 1;
  const int g = lane >> 4;
  const int lc = lane & 15;
  const int q = tid >> 2;
  const int slot = tid & 3;
  const int scs = (slot ^ ((q >> 1) & 3)) << 3;
  const int so = (g ^ ((lc >> 1) & 3)) << 3;

  u16* Ab = lds;            // 3 x [128][32]
  u16* Bbase = lds + 12288; // 3 x [128][32]
  u16 *Ac = Ab, *An = Ab + 4096, *Aw = Ab + 8192;
  u16 *Bc = Bbase, *Bn = Bbase + 4096, *Bw = Bbase + 8192;

  auto stage = [&](int kt, u16* At, u16* Bt) {
    const int kb = (kt << 5) + scs;
    GLD16(A + (size_t)(m0 + q) * K + kb,       At + q*32 + slot*8);
    GLD16(A + (size_t)(m0 + 64 + q) * K + kb,  At + (64 + q)*32 + slot*8);
    GLD16(Wt + (size_t)(n0 + q) * K + kb,      Bt + q*32 + slot*8);
    GLD16(Wt + (size_t)(n0 + 64 + q) * K + kb, Bt + (64 + q)*32 + slot*8);
  };

  f32x4 acc[4][4];
#pragma unroll
  for (int i = 0; i < 4; ++i)
#pragma unroll
    for (int j = 0; j < 4; ++j)
#pragma unroll
      for (int e = 0; e < 4; ++e) acc[i][j][e] = 0.f;

  const int KT = K >> 5;
  stage(0, Ac, Bc);
  stage(1, An, Bn);

  for (int kt = 0; kt < KT; ++kt) {
    if (kt + 1 < KT) wait_vmcnt<4>();
    else             wait_vmcnt<0>();
    wg_barrier();
    bf16x8 af[4], bfr[4];
#pragma unroll
    for (int i = 0; i < 4; ++i)
      af[i] = *(const bf16x8*)(Ac + (wm*64 + i*16 + lc)*32 + so);
#pragma unroll
    for (int j = 0; j < 4; ++j)
      bfr[j] = *(const bf16x8*)(Bc + (wn*64 + j*16 + lc)*32 + so);
    if (kt + 2 < KT) stage(kt + 2, Aw, Bw);
    __builtin_amdgcn_s_setprio(1);
#pragma unroll
    for (int i = 0; i < 4; ++i)
#pragma unroll
      for (int j = 0; j < 4; ++j)
        acc[i][j] = __builtin_amdgcn_mfma_f32_16x16x32_bf16(af[i], bfr[j], acc[i][j], 0, 0, 0);
    __builtin_amdgcn_s_setprio(0);
    u16* t;
    t = Ac; Ac = An; An = Aw; Aw = t;
    t = Bc; Bc = Bn; Bn = Bw; Bw = t;
  }

#pragma unroll
  for (int mi = 0; mi < 4; ++mi) {
#pragma unroll
    for (int ni = 0; ni < 4; ++ni) {
      const int n = n0 + wn*64 + ni*16 + lc;
      const int mbase = m0 + wm*64 + mi*16 + (g << 2);
      const float bia = bias[n];
#pragma unroll
      for (int e = 0; e < 4; ++e) {
        const size_t idx = (size_t)(mbase + e) * N + n;
        const float v = b2f(addb[idx]) + acc[mi][ni][e] + bia;
        if (FINAL) outf[idx] = v;
        else       outxb[idx] = f2b(v);
      }
    }
  }
}

// ---------------- RG-LRU chunked scan (bf16 z,u inputs): h_t = g*h_{t-1} + (1-g)*u ----
__global__ __launch_bounds__(256)
void scan1_k(const u16* __restrict__ zpre, const u16* __restrict__ u,
             float* __restrict__ aggA, float* __restrict__ aggB) {
  const int d = blockIdx.x * 256 + threadIdx.x;
  const int c = blockIdx.y, b = blockIdx.z;
  const size_t base = ((size_t)b * TT + (size_t)c * CHUNK) * DD + d;
  float a = 1.f, acc = 0.f;
  for (int t = 0; t < CHUNK; ++t) {
    const float gl = 1.f / (1.f + __expf(-b2f(zpre[base + (size_t)t * DD])));
    const float ul = b2f(u[base + (size_t)t * DD]);
    acc = gl * acc + (1.f - gl) * ul;
    a *= gl;
  }
  const size_t o = ((size_t)b * NCHUNK + c) * DD + d;
  aggA[o] = a; aggB[o] = acc;
}

__global__ __launch_bounds__(256)
void scan2_k(const float* __restrict__ aggA, const float* __restrict__ aggB,
             float* __restrict__ carry) {
  const int idx = blockIdx.x * 256 + threadIdx.x;  // b*DD + d
  const int b = idx >> 10, d = idx & 1023;
  float h = 0.f;
  for (int c = 0; c < NCHUNK; ++c) {
    const size_t o = ((size_t)b * NCHUNK + c) * DD + d;
    carry[o] = h;
    h = aggA[o] * h + aggB[o];
  }
}

__global__ __launch_bounds__(256)
void scan3_k(const u16* __restrict__ zpre, const u16* __restrict__ u,
             const float* __restrict__ carry, u16* __restrict__ hout) {
  const int d = blockIdx.x * 256 + threadIdx.x;
  const int c = blockIdx.y, b = blockIdx.z;
  const size_t base = ((size_t)b * TT + (size_t)c * CHUNK) * DD + d;
  float h = carry[((size_t)b * NCHUNK + c) * DD + d];
  for (int t = 0; t < CHUNK; ++t) {
    const float gl = 1.f / (1.f + __expf(-b2f(zpre[base + (size_t)t * DD])));
    const float ul = b2f(u[base + (size_t)t * DD]);
    h = gl * h + (1.f - gl) * ul;
    hout[base + (size_t)t * DD] = f2b(h);
  }
}

// ---------------- MFMA local-window attention ----------------
__global__ __launch_bounds__(256)
void attn_mfma(const u16* __restrict__ qkb, const u16* __restrict__ vt,
               u16* __restrict__ y) {
  __shared__ u16 kv[16384];
  __shared__ u16 pb[4][16][200];
  const int tid = threadIdx.x;
  const int lane = tid & 63;
  const int wid = tid >> 6;
  const int g = lane >> 4;
  const int lc = lane & 15;
  const int t0 = blockIdx.x << 6;
  const int bh = blockIdx.y;
  const int bT = (bh >> 2) * TT;
  const int h = bh & 3;

  bf16x8 afq[8];
  {
    const u16* qg = qkb + (size_t)(bT + t0 + wid*16 + lc) * 2048 + h*256 + g*8;
#pragma unroll
    for (int ks = 0; ks < 8; ++ks)
      afq[ks] = __builtin_bit_cast(bf16x8, *(const uint4*)(qg + ks*32));
  }

  f32x4 sc[12];
#pragma unroll
  for (int f = 0; f < 12; ++f)
#pragma unroll
    for (int e = 0; e < 4; ++e) sc[f][e] = 0.f;

  const int koff = 1024 + h*256;
#pragma unroll
  for (int c = 0; c < 3; ++c) {
    const int j0 = t0 + (c - 2) * 64;
    if (j0 < 0) {
#pragma unroll
      for (int nt = 0; nt < 4; ++nt)
#pragma unroll
        for (int e = 0; e < 4; ++e) sc[c*4+nt][e] = -1e30f;
      continue;
    }
    __syncthreads();
    {
      const u16* kg = qkb + (size_t)(bT + j0) * 2048 + koff;
#pragma unroll
      for (int i = 0; i < 8; ++i) {
        const int o16 = i*256 + tid;
        const int slab = o16 >> 8, key = (o16 >> 2) & 63, ds = o16 & 3;
        GLD16(kg + (size_t)key*2048 + slab*32 + ds*8, kv + o16*8);
      }
    }
    __syncthreads();
#pragma unroll
    for (int nt = 0; nt < 4; ++nt) {
      f32x4 s = sc[c*4+nt];
#pragma unroll
      for (int ks = 0; ks < 8; ++ks) {
        const bf16x8 kb = *(const bf16x8*)(kv + ks*2048 + (nt*16 + lc)*32 + g*8);
        s = __builtin_amdgcn_mfma_f32_16x16x32_bf16(afq[ks], kb, s, 0, 0, 0);
      }
      sc[c*4+nt] = s;
    }
#pragma unroll
    for (int nt = 0; nt < 4; ++nt)
#pragma unroll
      for (int e = 0; e < 4; ++e) {
        const int tl = wid*16 + g*4 + e;
        const int jl = nt*16 + lc;
        const bool ok = (c == 1) || (c == 2 ? (jl <= tl) : (jl >= tl + 1));
        sc[c*4+nt][e] = ok ? sc[c*4+nt][e] * 0.0625f : -1e30f;
      }
  }

#pragma unroll
  for (int e = 0; e < 4; ++e) {
    float m = -1e30f;
#pragma unroll
    for (int f = 0; f < 12; ++f) m = fmaxf(m, sc[f][e]);
    m = fmaxf(m, __shfl_xor(m, 1)); m = fmaxf(m, __shfl_xor(m, 2));
    m = fmaxf(m, __shfl_xor(m, 4)); m = fmaxf(m, __shfl_xor(m, 8));
    float s = 0.f;
#pragma unroll
    for (int f = 0; f < 12; ++f) { const float p = __expf(sc[f][e] - m); sc[f][e] = p; s += p; }
    s += __shfl_xor(s, 1); s += __shfl_xor(s, 2);
    s += __shfl_xor(s, 4); s += __shfl_xor(s, 8);
    const float is = 1.f / s;
#pragma unroll
    for (int f = 0; f < 12; ++f) sc[f][e] *= is;
  }
#pragma unroll
  for (int c = 0; c < 3; ++c)
#pragma unroll
    for (int nt = 0; nt < 4; ++nt)
#pragma unroll
      for (int e = 0; e < 4; ++e)
        pb[wid][g*4 + e][c*64 + nt*16 + lc] = f2b(sc[c*4+nt][e]);

  f32x4 acc[16];
#pragma unroll
  for (int nt = 0; nt < 16; ++nt)
#pragma unroll
    for (int e = 0; e < 4; ++e) acc[nt][e] = 0.f;

  const u16* vg = vt + (size_t)bh * 256 * 2048;
#pragma unroll
  for (int c = 0; c < 3; ++c) {
    const int j0 = t0 + (c - 2) * 64;
    if (j0 < 0) continue;
    __syncthreads();
#pragma unroll
    for (int i = 0; i < 8; ++i) {
      const int o16 = i*256 + tid;
      const int dim = o16 >> 3, slot = o16 & 7;
      const int ss = slot ^ (dim & 7);
      GLD16(vg + (size_t)dim*2048 + j0 + ss*8, kv + o16*8);
    }
    __syncthreads();
#pragma unroll
    for (int ks = 0; ks < 2; ++ks) {
      const bf16x8 pa = *(const bf16x8*)&pb[wid][lc][(c*2 + ks)*32 + g*8];
#pragma unroll
      for (int nt = 0; nt < 16; ++nt) {
        const int dim = nt*16 + lc;
        int boff = dim*128 + ks*64 + g*16;
        boff ^= (dim & 7) << 4;
        const bf16x8 vb = *(const bf16x8*)((const char*)kv + boff);
        acc[nt] = __builtin_amdgcn_mfma_f32_16x16x32_bf16(pa, vb, acc[nt], 0, 0, 0);
      }
    }
  }

#pragma unroll
  for (int nt = 0; nt < 16; ++nt)
#pragma unroll
    for (int e = 0; e < 4; ++e) {
      const int tok = bT + t0 + wid*16 + g*4 + e;
      y[(size_t)tok * 1024 + h*256 + nt*16 + lc] = f2b(acc[nt][e]);
    }
}

// ---------------- host orchestration ----------------
extern "C" void kernel_launch(void* const* d_in, const int* in_sizes, int n_in,
                              void* d_out, int out_size, void* d_ws, size_t ws_size,
                              hipStream_t stream) {
  const float* x_in      = (const float*)d_in[0];
  const float* ln1_s     = (const float*)d_in[1];
  const float* ln1_b     = (const float*)d_in[2];
  const float* ln2_s     = (const float*)d_in[3];
  const float* ln2_b     = (const float*)d_in[4];
  const float* ln3_s     = (const float*)d_in[5];
  const float* ln3_b     = (const float*)d_in[6];
  const float* rg_in_w   = (const float*)d_in[7];
  const float* rg_in_b   = (const float*)d_in[8];
  const float* rg_gate_w = (const float*)d_in[9];
  const float* rg_gate_b = (const float*)d_in[10];
  const float* rg_out_w  = (const float*)d_in[11];
  const float* rg_out_b  = (const float*)d_in[12];
  const float* qkv_w     = (const float*)d_in[13];
  const float* qkv_b     = (const float*)d_in[14];
  const float* attn_out_w= (const float*)d_in[15];
  const float* attn_out_b= (const float*)d_in[16];
  const float* mlp_w1    = (const float*)d_in[17];
  const float* mlp_b1    = (const float*)d_in[18];
  const float* mlp_w2    = (const float*)d_in[19];
  const float* mlp_b2    = (const float*)d_in[20];

  hipFuncSetAttribute((const void*)&gemm256t<2>, hipFuncAttributeMaxDynamicSharedMemorySize, 73728);
  hipFuncSetAttribute((const void*)&gemm256t<4>, hipFuncAttributeMaxDynamicSharedMemorySize, 73728);
  hipFuncSetAttribute((const void*)&gemm256t<5>, hipFuncAttributeMaxDynamicSharedMemorySize, 73728);
  hipFuncSetAttribute((const void*)&gemm128t<0>, hipFuncAttributeMaxDynamicSharedMemorySize, 49152);
  hipFuncSetAttribute((const void*)&gemm128t<1>, hipFuncAttributeMaxDynamicSharedMemorySize, 49152);

  float* xout = (float*)d_out;
  char* ws = (char*)d_ws;
  u16*  wt     = (u16*)ws;                          // 62,914,560 B (bf16 transposed weights)
  u16*  xn     = (u16*)(ws + 62914560);             // 16,777,216 B
  char* bigS   = ws + 62914560 + 16777216;          // 67,108,864 B
  char* smallS = bigS + 67108864;                   // 16,777,216 B
  float* aggA  = (float*)(smallS + 16777216);
  float* aggB  = aggA + (size_t)BB * NCHUNK * DD;
  float* carry = aggB + (size_t)BB * NCHUNK * DD;
  u16*  xb     = (u16*)(carry + (size_t)BB * NCHUNK * DD);  // 16,777,216 B bf16 residual

  u16* ubuf = (u16*)bigS;                           // RG phase (bf16)
  u16* zbuf = (u16*)(bigS + 33554432);              // pre-sigmoid gate, bf16
  u16* qkb  = (u16*)bigS;                           // attn phase: [8192][2048] QK
  u16* vtb  = (u16*)(bigS + 33554432);              // attn phase: V transposed, 16MB
  u16* hid  = (u16*)bigS;                           // MLP phase
  u16* hbuf = (u16*)smallS;
  u16* ybuf = (u16*)smallS;

  const size_t LW = 15728640;
  const dim3 tb(32, 8);
  // batched over both layers via blockIdx.z
  transpose_cvt<<<dim3(32, 32, 2),  tb, 0, stream>>>(rg_in_w,    wt + 0,        DD, DD,   DD*DD,   LW);
  transpose_cvt<<<dim3(32, 32, 2),  tb, 0, stream>>>(rg_gate_w,  wt + 1048576,  DD, DD,   DD*DD,   LW);
  transpose_cvt<<<dim3(32, 32, 2),  tb, 0, stream>>>(rg_out_w,   wt + 2097152,  DD, DD,   DD*DD,   LW);
  transpose_cvt<<<dim3(96, 32, 2),  tb, 0, stream>>>(qkv_w,      wt + 3145728,  DD, 3072, DD*3072, LW);
  transpose_cvt<<<dim3(32, 32, 2),  tb, 0, stream>>>(attn_out_w, wt + 6291456,  DD, DD,   DD*DD,   LW);
  transpose_cvt<<<dim3(128, 32, 2), tb, 0, stream>>>(mlp_w1,     wt + 7340032,  DD, 4096, DD*4096, LW);
  transpose_cvt<<<dim3(32, 128, 2), tb, 0, stream>>>(mlp_w2,     wt + 11534336, 4096, DD, 4096*DD, LW);
  cast_k<<<4096, 256, 0, stream>>>(x_in, xb);

  for (int l = 0; l < NLAYER; ++l) {
    u16* base = wt + (size_t)l * LW;
    // ---- RG-LRU block (rg_in + rg_gate fused; u and pre-sigmoid z stored bf16)
    ln_k<<<MM, 256, 0, stream>>>(xb, ln1_s + l*DD, ln1_b + l*DD, xn);
    gemm256t<5><<<dim3(16, 32), 512, 73728, stream>>>(xn, base + 0, rg_in_b + l*DD, rg_gate_b + l*DD,
                                                      (float*)zbuf, ubuf, DD, 2048);
    scan1_k<<<dim3(4, NCHUNK, BB), 256, 0, stream>>>(zbuf, ubuf, aggA, aggB);
    scan2_k<<<16, 256, 0, stream>>>(aggA, aggB, carry);
    scan3_k<<<dim3(4, NCHUNK, BB), 256, 0, stream>>>(zbuf, ubuf, carry, hbuf);
    gemm128t<0><<<dim3(8, 64), 256, 49152, stream>>>(hbuf, base + 2097152, rg_out_b + l*DD,
                                                     xb, nullptr, xb, DD, 1024);
    // ---- local attention block
    ln_k<<<MM, 256, 0, stream>>>(xb, ln2_s + l*DD, ln2_b + l*DD, xn);
    gemm256t<4><<<dim3(24, 32), 512, 73728, stream>>>(xn, base + 3145728, qkv_b + l*3072, nullptr,
                                                      (float*)vtb, qkb, DD, 3072);
    attn_mfma<<<dim3(TT/64, BB*HH), 256, 0, stream>>>(qkb, vtb, ybuf);
    gemm128t<0><<<dim3(8, 64), 256, 49152, stream>>>(ybuf, base + 6291456, attn_out_b + l*DD,
                                                     xb, nullptr, xb, DD, 1024);
    // ---- MLP block
    ln_k<<<MM, 256, 0, stream>>>(xb, ln3_s + l*DD, ln3_b + l*DD, xn);
    gemm256t<2><<<dim3(32, 32), 512, 73728, stream>>>(xn, base + 7340032, mlp_b1 + l*4096, nullptr,
                                                      nullptr, hid, DD, 4096);
    if (l == NLAYER - 1)
      gemm128t<1><<<dim3(8, 64), 256, 49152, stream>>>(hid, base + 11534336, mlp_b2 + l*DD,
                                                       xb, xout, nullptr, 4096, 1024);
    else
      gemm128t<0><<<dim3(8, 64), 256, 49152, stream>>>(hid, base + 11534336, mlp_b2 + l*DD,
                                                       xb, nullptr, xb, 4096, 1024);
  }
}

// Round 17
// 827.577 us; speedup vs baseline: 1.0682x; 1.0128x over previous
//
#include <hip/hip_runtime.h>
#include <math.h>

#define DD 1024
#define TT 2048
#define BB 4
#define HH 4
#define HDIM 256
#define NLAYER 2
#define MM (BB*TT)          // 8192 rows
#define NCHUNK 32
#define CHUNK (TT/NCHUNK)   // 64

typedef unsigned short u16;
typedef __bf16 bf16x8 __attribute__((ext_vector_type(8)));
typedef float f32x4 __attribute__((ext_vector_type(4)));

__device__ __forceinline__ float b2f(u16 h) {
  unsigned u = ((unsigned)h) << 16;
  return __builtin_bit_cast(float, u);
}
__device__ __forceinline__ u16 f2b(float f) {
  unsigned u = __builtin_bit_cast(unsigned, f);
  u += 0x7fffu + ((u >> 16) & 1u);
  return (u16)(u >> 16);
}
__device__ __forceinline__ float blo(unsigned u) { return __builtin_bit_cast(float, u << 16); }
__device__ __forceinline__ float bhi(unsigned u) { return __builtin_bit_cast(float, u & 0xffff0000u); }

#define GLD16(g, l) __builtin_amdgcn_global_load_lds( \
    (__attribute__((address_space(1))) void*)(void*)(g), \
    (__attribute__((address_space(3))) void*)(l), 16, 0, 0)

__device__ __forceinline__ void wg_barrier() {
  asm volatile("" ::: "memory");
  __builtin_amdgcn_s_barrier();
  asm volatile("" ::: "memory");
}
template<int N> __device__ __forceinline__ void wait_vmcnt() {
  asm volatile("s_waitcnt vmcnt(%0)" :: "i"(N) : "memory");
}

// ------- weight fp32 -> bf16 transpose: Wt[N][K] = W[K][N], batched over layers -------
__global__ __launch_bounds__(256)
void transpose_cvt(const float* __restrict__ W, u16* __restrict__ Wt, int K, int N,
                   size_t lsrc, size_t ldst) {
  __shared__ float tile[32][33];
  const float* Wl = W + (size_t)blockIdx.z * lsrc;
  u16* Wtl = Wt + (size_t)blockIdx.z * ldst;
  const int n0 = blockIdx.x << 5, k0 = blockIdx.y << 5;
  const int tx = threadIdx.x, ty = threadIdx.y;
#pragma unroll
  for (int i = 0; i < 4; ++i)
    tile[ty + i*8][tx] = Wl[(size_t)(k0 + ty + i*8) * N + n0 + tx];
  __syncthreads();
#pragma unroll
  for (int i = 0; i < 4; ++i)
    Wtl[(size_t)(n0 + ty + i*8) * K + k0 + tx] = f2b(tile[tx][ty + i*8]);
}

// ---- first LayerNorm: reads fp32 x_in, writes bf16 LN output AND bf16 residual copy ----
__global__ __launch_bounds__(256)
void ln_first_k(const float* __restrict__ x, const float* __restrict__ sc,
                const float* __restrict__ bi, u16* __restrict__ xn, u16* __restrict__ xb) {
  const int row = blockIdx.x;
  const int tid = threadIdx.x;
  const float4 xv = ((const float4*)(x + (size_t)row * DD))[tid];
  float s = xv.x + xv.y + xv.z + xv.w;
  float q = xv.x*xv.x + xv.y*xv.y + xv.z*xv.z + xv.w*xv.w;
#pragma unroll
  for (int o = 1; o < 64; o <<= 1) { s += __shfl_xor(s, o); q += __shfl_xor(q, o); }
  __shared__ float rs[4], rq[4];
  if ((tid & 63) == 0) { rs[tid >> 6] = s; rq[tid >> 6] = q; }
  __syncthreads();
  s = rs[0] + rs[1] + rs[2] + rs[3];
  q = rq[0] + rq[1] + rq[2] + rq[3];
  const float mean = s * (1.f / DD);
  const float var = q * (1.f / DD) - mean * mean;
  const float rstd = rsqrtf(var + 1e-5f);
  const float4 sv = ((const float4*)sc)[tid];
  const float4 bv = ((const float4*)bi)[tid];
  uint2 pk, pb;
  pk.x = (unsigned)f2b((xv.x - mean) * rstd * sv.x + bv.x)
       | ((unsigned)f2b((xv.y - mean) * rstd * sv.y + bv.y) << 16);
  pk.y = (unsigned)f2b((xv.z - mean) * rstd * sv.z + bv.z)
       | ((unsigned)f2b((xv.w - mean) * rstd * sv.w + bv.w) << 16);
  pb.x = (unsigned)f2b(xv.x) | ((unsigned)f2b(xv.y) << 16);
  pb.y = (unsigned)f2b(xv.z) | ((unsigned)f2b(xv.w) << 16);
  *(uint2*)(xn + (size_t)row * DD + (tid << 2)) = pk;
  *(uint2*)(xb + (size_t)row * DD + (tid << 2)) = pb;
}

// ---------------- LayerNorm (bf16 residual in, bf16 out) ----------------
__global__ __launch_bounds__(256)
void ln_k(const u16* __restrict__ xb, const float* __restrict__ sc,
          const float* __restrict__ bi, u16* __restrict__ xn) {
  const int row = blockIdx.x;
  const int tid = threadIdx.x;
  const uint2 rv = ((const uint2*)(xb + (size_t)row * DD))[tid];
  const float x0 = blo(rv.x), x1 = bhi(rv.x), x2 = blo(rv.y), x3 = bhi(rv.y);
  float s = x0 + x1 + x2 + x3;
  float q = x0*x0 + x1*x1 + x2*x2 + x3*x3;
#pragma unroll
  for (int o = 1; o < 64; o <<= 1) { s += __shfl_xor(s, o); q += __shfl_xor(q, o); }
  __shared__ float rs[4], rq[4];
  if ((tid & 63) == 0) { rs[tid >> 6] = s; rq[tid >> 6] = q; }
  __syncthreads();
  s = rs[0] + rs[1] + rs[2] + rs[3];
  q = rq[0] + rq[1] + rq[2] + rq[3];
  const float mean = s * (1.f / DD);
  const float var = q * (1.f / DD) - mean * mean;
  const float rstd = rsqrtf(var + 1e-5f);
  const float4 sv = ((const float4*)sc)[tid];
  const float4 bv = ((const float4*)bi)[tid];
  const u16 o0 = f2b((x0 - mean) * rstd * sv.x + bv.x);
  const u16 o1 = f2b((x1 - mean) * rstd * sv.y + bv.y);
  const u16 o2 = f2b((x2 - mean) * rstd * sv.z + bv.z);
  const u16 o3 = f2b((x3 - mean) * rstd * sv.w + bv.w);
  uint2 pk;
  pk.x = (unsigned)o0 | ((unsigned)o1 << 16);
  pk.y = (unsigned)o2 | ((unsigned)o3 << 16);
  *(uint2*)(xn + (size_t)row * DD + (tid << 2)) = pk;
}

// ======== 256x128 8-wave GEMM, 16x16x32, BK=32, 3-buffer LDS (wide GEMMs) ========
// Waves tile 64x64 (4M x 2N): 8 ds_reads + 16 MFMA per wave per K-tile.
// C[M,N] = A[M,K]*Wt[N,K]^T + bias.  512 threads, 72KB dynamic LDS.
// EPI: 2 = bf16 gelu store, 4 = qkv split (QK rowmajor + V^T), 5 = dual bf16 store
template<int EPI>
__global__ __launch_bounds__(512, 4)
void gemm256t(const u16* __restrict__ A, const u16* __restrict__ Wt,
              const float* __restrict__ bias, const float* __restrict__ bias2,
              float* __restrict__ outf, u16* __restrict__ outb, int K, int N) {
  extern __shared__ u16 lds[];
  const int tid = threadIdx.x;
  const int gx = gridDim.x;
  const int nwg = gx * (int)gridDim.y;
  int lid = (int)blockIdx.y * gx + (int)blockIdx.x;
  lid = (lid & 7) * (nwg >> 3) + (lid >> 3);     // XCD-chunked (nwg % 8 == 0)
  const int m0 = (lid / gx) << 8;
  const int n0 = (lid % gx) << 7;
  const int lane = tid & 63;
  const int wid = tid >> 6;
  const int wm = wid >> 1;          // 0..3 -> 64-row band
  const int wn = wid & 1;           // 0..1 -> 64-col band
  const int g = lane >> 4;
  const int lc = lane & 15;
  const int q = tid >> 2;
  const int slot = tid & 3;
  const int scs = (slot ^ ((q >> 1) & 3)) << 3;
  const int so = (g ^ ((lc >> 1) & 3)) << 3;

  u16* Ab = lds;            // 3 x [256][32]
  u16* Bbase = lds + 24576; // 3 x [128][32]
  u16 *Ac = Ab, *An = Ab + 8192, *Aw = Ab + 16384;
  u16 *Bc = Bbase, *Bn = Bbase + 4096, *Bw = Bbase + 8192;

  auto stage = [&](int kt, u16* At, u16* Bt) {
    const int kb = (kt << 5) + scs;
    GLD16(A + (size_t)(m0 + q) * K + kb,       At + q*32 + slot*8);
    GLD16(A + (size_t)(m0 + 128 + q) * K + kb, At + (128 + q)*32 + slot*8);
    GLD16(Wt + (size_t)(n0 + q) * K + kb,      Bt + q*32 + slot*8);
  };

  f32x4 acc[4][4];
#pragma unroll
  for (int i = 0; i < 4; ++i)
#pragma unroll
    for (int j = 0; j < 4; ++j)
#pragma unroll
      for (int e = 0; e < 4; ++e) acc[i][j][e] = 0.f;

  const int KT = K >> 5;
  stage(0, Ac, Bc);
  stage(1, An, Bn);

  for (int kt = 0; kt < KT; ++kt) {
    if (kt + 1 < KT) wait_vmcnt<3>();
    else             wait_vmcnt<0>();
    wg_barrier();
    bf16x8 af[4], bfr[4];
#pragma unroll
    for (int i = 0; i < 4; ++i)
      af[i] = *(const bf16x8*)(Ac + (wm*64 + i*16 + lc)*32 + so);
#pragma unroll
    for (int j = 0; j < 4; ++j)
      bfr[j] = *(const bf16x8*)(Bc + (wn*64 + j*16 + lc)*32 + so);
    if (kt + 2 < KT) stage(kt + 2, Aw, Bw);
    __builtin_amdgcn_s_setprio(1);
#pragma unroll
    for (int i = 0; i < 4; ++i)
#pragma unroll
      for (int j = 0; j < 4; ++j)
        acc[i][j] = __builtin_amdgcn_mfma_f32_16x16x32_bf16(af[i], bfr[j], acc[i][j], 0, 0, 0);
    __builtin_amdgcn_s_setprio(0);
    u16* t;
    t = Ac; Ac = An; An = Aw; Aw = t;
    t = Bc; Bc = Bn; Bn = Bw; Bw = t;
  }

#pragma unroll
  for (int mi = 0; mi < 4; ++mi) {
#pragma unroll
    for (int ni = 0; ni < 4; ++ni) {
      const int n = n0 + wn*64 + ni*16 + lc;
      const int mbase = m0 + wm*64 + mi*16 + (g << 2);
      if (EPI == 4) {
        const float bia = bias[n];
        if (n < 2048) {
#pragma unroll
          for (int e = 0; e < 4; ++e)
            outb[(size_t)(mbase + e) * 2048 + n] = f2b(acc[mi][ni][e] + bia);
        } else {
          const int hh = (n - 2048) >> 8, dim = (n - 2048) & 255;
          const int bidx = mbase >> 11, t = mbase & 2047;
          const u16 a0 = f2b(acc[mi][ni][0] + bia);
          const u16 a1 = f2b(acc[mi][ni][1] + bia);
          const u16 a2 = f2b(acc[mi][ni][2] + bia);
          const u16 a3 = f2b(acc[mi][ni][3] + bia);
          uint2 pk;
          pk.x = (unsigned)a0 | ((unsigned)a1 << 16);
          pk.y = (unsigned)a2 | ((unsigned)a3 << 16);
          u16* vtp = (u16*)outf;
          *(uint2*)(vtp + ((size_t)((bidx*4 + hh)*256 + dim)) * 2048 + t) = pk;
        }
      } else if (EPI == 5) {
        const float bia = (n < 1024) ? bias[n] : bias2[n - 1024];
        u16* dst = (n < 1024) ? outb : (u16*)outf;
        const int nn = n & 1023;
#pragma unroll
        for (int e = 0; e < 4; ++e)
          dst[(size_t)(mbase + e) * 1024 + nn] = f2b(acc[mi][ni][e] + bia);
      } else {  // EPI == 2
        const float bia = bias[n];
#pragma unroll
        for (int e = 0; e < 4; ++e) {
          const float v = acc[mi][ni][e] + bia;
          const float zc = fminf(fmaxf(1.5957691216f * (v + 0.044715f*v*v*v), -30.f), 30.f);
          outb[(size_t)(mbase + e) * N + n] = f2b(v / (1.f + __expf(-zc)));
        }
      }
    }
  }
}

// ======== 128x128 4-wave GEMM (N=1024 residual GEMMs), bf16 residual stream ========
// out = addb(bf16) + A*Wt^T + bias.  FINAL=0: write bf16 xb; FINAL=1: write fp32 d_out.
template<int FINAL>
__global__ __launch_bounds__(256, 2)
void gemm128t(const u16* __restrict__ A, const u16* __restrict__ Wt,
              const float* __restrict__ bias, const u16* __restrict__ addb,
              float* __restrict__ outf, u16* __restrict__ outxb, int K, int N) {
  extern __shared__ u16 lds[];
  const int tid = threadIdx.x;
  const int gx = gridDim.x;  // 8
  const int nwg = gx * (int)gridDim.y;
  int lid = (int)blockIdx.y * gx + (int)blockIdx.x;
  lid = (lid & 7) * (nwg >> 3) + (lid >> 3);
  const int m0 = (lid / gx) << 7;
  const int n0 = (lid % gx) << 7;
  const int lane = tid & 63;
  const int wid = tid >> 6;
  const int wm = wid >> 1;
  const int wn = wid & 1;
  const int g = lane >> 4;
  const int lc = lane & 15;
  const int q = tid >> 2;
  const int slot = tid & 3;
  const int scs = (slot ^ ((q >> 1) & 3)) << 3;
  const int so = (g ^ ((lc >> 1) & 3)) << 3;

  u16* Ab = lds;            // 3 x [128][32]
  u16* Bbase = lds + 12288; // 3 x [128][32]
  u16 *Ac = Ab, *An = Ab + 4096, *Aw = Ab + 8192;
  u16 *Bc = Bbase, *Bn = Bbase + 4096, *Bw = Bbase + 8192;

  auto stage = [&](int kt, u16* At, u16* Bt) {
    const int kb = (kt << 5) + scs;
    GLD16(A + (size_t)(m0 + q) * K + kb,       At + q*32 + slot*8);
    GLD16(A + (size_t)(m0 + 64 + q) * K + kb,  At + (64 + q)*32 + slot*8);
    GLD16(Wt + (size_t)(n0 + q) * K + kb,      Bt + q*32 + slot*8);
    GLD16(Wt + (size_t)(n0 + 64 + q) * K + kb, Bt + (64 + q)*32 + slot*8);
  };

  f32x4 acc[4][4];
#pragma unroll
  for (int i = 0; i < 4; ++i)
#pragma unroll
    for (int j = 0; j < 4; ++j)
#pragma unroll
      for (int e = 0; e < 4; ++e) acc[i][j][e] = 0.f;

  const int KT = K >> 5;
  stage(0, Ac, Bc);
  stage(1, An, Bn);

  for (int kt = 0; kt < KT; ++kt) {
    if (kt + 1 < KT) wait_vmcnt<4>();
    else             wait_vmcnt<0>();
    wg_barrier();
    bf16x8 af[4], bfr[4];
#pragma unroll
    for (int i = 0; i < 4; ++i)
      af[i] = *(const bf16x8*)(Ac + (wm*64 + i*16 + lc)*32 + so);
#pragma unroll
    for (int j = 0; j < 4; ++j)
      bfr[j] = *(const bf16x8*)(Bc + (wn*64 + j*16 + lc)*32 + so);
    if (kt + 2 < KT) stage(kt + 2, Aw, Bw);
    __builtin_amdgcn_s_setprio(1);
#pragma unroll
    for (int i = 0; i < 4; ++i)
#pragma unroll
      for (int j = 0; j < 4; ++j)
        acc[i][j] = __builtin_amdgcn_mfma_f32_16x16x32_bf16(af[i], bfr[j], acc[i][j], 0, 0, 0);
    __builtin_amdgcn_s_setprio(0);
    u16* t;
    t = Ac; Ac = An; An = Aw; Aw = t;
    t = Bc; Bc = Bn; Bn = Bw; Bw = t;
  }

#pragma unroll
  for (int mi = 0; mi < 4; ++mi) {
#pragma unroll
    for (int ni = 0; ni < 4; ++ni) {
      const int n = n0 + wn*64 + ni*16 + lc;
      const int mbase = m0 + wm*64 + mi*16 + (g << 2);
      const float bia = bias[n];
#pragma unroll
      for (int e = 0; e < 4; ++e) {
        const size_t idx = (size_t)(mbase + e) * N + n;
        const float v = b2f(addb[idx]) + acc[mi][ni][e] + bia;
        if (FINAL) outf[idx] = v;
        else       outxb[idx] = f2b(v);
      }
    }
  }
}

// ---------------- RG-LRU chunked scan (bf16 z,u inputs): h_t = g*h_{t-1} + (1-g)*u ----
__global__ __launch_bounds__(256)
void scan1_k(const u16* __restrict__ zpre, const u16* __restrict__ u,
             float* __restrict__ aggA, float* __restrict__ aggB) {
  const int d = blockIdx.x * 256 + threadIdx.x;
  const int c = blockIdx.y, b = blockIdx.z;
  const size_t base = ((size_t)b * TT + (size_t)c * CHUNK) * DD + d;
  float a = 1.f, acc = 0.f;
  for (int t = 0; t < CHUNK; ++t) {
    const float gl = 1.f / (1.f + __expf(-b2f(zpre[base + (size_t)t * DD])));
    const float ul = b2f(u[base + (size_t)t * DD]);
    acc = gl * acc + (1.f - gl) * ul;
    a *= gl;
  }
  const size_t o = ((size_t)b * NCHUNK + c) * DD + d;
  aggA[o] = a; aggB[o] = acc;
}

__global__ __launch_bounds__(256)
void scan2_k(const float* __restrict__ aggA, const float* __restrict__ aggB,
             float* __restrict__ carry) {
  const int idx = blockIdx.x * 256 + threadIdx.x;  // b*DD + d
  const int b = idx >> 10, d = idx & 1023;
  float h = 0.f;
  for (int c = 0; c < NCHUNK; ++c) {
    const size_t o = ((size_t)b * NCHUNK + c) * DD + d;
    carry[o] = h;
    h = aggA[o] * h + aggB[o];
  }
}

__global__ __launch_bounds__(256)
void scan3_k(const u16* __restrict__ zpre, const u16* __restrict__ u,
             const float* __restrict__ carry, u16* __restrict__ hout) {
  const int d = blockIdx.x * 256 + threadIdx.x;
  const int c = blockIdx.y, b = blockIdx.z;
  const size_t base = ((size_t)b * TT + (size_t)c * CHUNK) * DD + d;
  float h = carry[((size_t)b * NCHUNK + c) * DD + d];
  for (int t = 0; t < CHUNK; ++t) {
    const float gl = 1.f / (1.f + __expf(-b2f(zpre[base + (size_t)t * DD])));
    const float ul = b2f(u[base + (size_t)t * DD]);
    h = gl * h + (1.f - gl) * ul;
    hout[base + (size_t)t * DD] = f2b(h);
  }
}

// ---------------- MFMA local-window attention ----------------
__global__ __launch_bounds__(256)
void attn_mfma(const u16* __restrict__ qkb, const u16* __restrict__ vt,
               u16* __restrict__ y) {
  __shared__ u16 kv[16384];
  __shared__ u16 pb[4][16][200];
  const int tid = threadIdx.x;
  const int lane = tid & 63;
  const int wid = tid >> 6;
  const int g = lane >> 4;
  const int lc = lane & 15;
  const int t0 = blockIdx.x << 6;
  const int bh = blockIdx.y;
  const int bT = (bh >> 2) * TT;
  const int h = bh & 3;

  bf16x8 afq[8];
  {
    const u16* qg = qkb + (size_t)(bT + t0 + wid*16 + lc) * 2048 + h*256 + g*8;
#pragma unroll
    for (int ks = 0; ks < 8; ++ks)
      afq[ks] = __builtin_bit_cast(bf16x8, *(const uint4*)(qg + ks*32));
  }

  f32x4 sc[12];
#pragma unroll
  for (int f = 0; f < 12; ++f)
#pragma unroll
    for (int e = 0; e < 4; ++e) sc[f][e] = 0.f;

  const int koff = 1024 + h*256;
#pragma unroll
  for (int c = 0; c < 3; ++c) {
    const int j0 = t0 + (c - 2) * 64;
    if (j0 < 0) {
#pragma unroll
      for (int nt = 0; nt < 4; ++nt)
#pragma unroll
        for (int e = 0; e < 4; ++e) sc[c*4+nt][e] = -1e30f;
      continue;
    }
    __syncthreads();
    {
      const u16* kg = qkb + (size_t)(bT + j0) * 2048 + koff;
#pragma unroll
      for (int i = 0; i < 8; ++i) {
        const int o16 = i*256 + tid;
        const int slab = o16 >> 8, key = (o16 >> 2) & 63, ds = o16 & 3;
        GLD16(kg + (size_t)key*2048 + slab*32 + ds*8, kv + o16*8);
      }
    }
    __syncthreads();
#pragma unroll
    for (int nt = 0; nt < 4; ++nt) {
      f32x4 s = sc[c*4+nt];
#pragma unroll
      for (int ks = 0; ks < 8; ++ks) {
        const bf16x8 kb = *(const bf16x8*)(kv + ks*2048 + (nt*16 + lc)*32 + g*8);
        s = __builtin_amdgcn_mfma_f32_16x16x32_bf16(afq[ks], kb, s, 0, 0, 0);
      }
      sc[c*4+nt] = s;
    }
#pragma unroll
    for (int nt = 0; nt < 4; ++nt)
#pragma unroll
      for (int e = 0; e < 4; ++e) {
        const int tl = wid*16 + g*4 + e;
        const int jl = nt*16 + lc;
        const bool ok = (c == 1) || (c == 2 ? (jl <= tl) : (jl >= tl + 1));
        sc[c*4+nt][e] = ok ? sc[c*4+nt][e] * 0.0625f : -1e30f;
      }
  }

#pragma unroll
  for (int e = 0; e < 4; ++e) {
    float m = -1e30f;
#pragma unroll
    for (int f = 0; f < 12; ++f) m = fmaxf(m, sc[f][e]);
    m = fmaxf(m, __shfl_xor(m, 1)); m = fmaxf(m, __shfl_xor(m, 2));
    m = fmaxf(m, __shfl_xor(m, 4)); m = fmaxf(m, __shfl_xor(m, 8));
    float s = 0.f;
#pragma unroll
    for (int f = 0; f < 12; ++f) { const float p = __expf(sc[f][e] - m); sc[f][e] = p; s += p; }
    s += __shfl_xor(s, 1); s += __shfl_xor(s, 2);
    s += __shfl_xor(s, 4); s += __shfl_xor(s, 8);
    const float is = 1.f / s;
#pragma unroll
    for (int f = 0; f < 12; ++f) sc[f][e] *= is;
  }
#pragma unroll
  for (int c = 0; c < 3; ++c)
#pragma unroll
    for (int nt = 0; nt < 4; ++nt)
#pragma unroll
      for (int e = 0; e < 4; ++e)
        pb[wid][g*4 + e][c*64 + nt*16 + lc] = f2b(sc[c*4+nt][e]);

  f32x4 acc[16];
#pragma unroll
  for (int nt = 0; nt < 16; ++nt)
#pragma unroll
    for (int e = 0; e < 4; ++e) acc[nt][e] = 0.f;

  const u16* vg = vt + (size_t)bh * 256 * 2048;
#pragma unroll
  for (int c = 0; c < 3; ++c) {
    const int j0 = t0 + (c - 2) * 64;
    if (j0 < 0) continue;
    __syncthreads();
#pragma unroll
    for (int i = 0; i < 8; ++i) {
      const int o16 = i*256 + tid;
      const int dim = o16 >> 3, slot = o16 & 7;
      const int ss = slot ^ (dim & 7);
      GLD16(vg + (size_t)dim*2048 + j0 + ss*8, kv + o16*8);
    }
    __syncthreads();
#pragma unroll
    for (int ks = 0; ks < 2; ++ks) {
      const bf16x8 pa = *(const bf16x8*)&pb[wid][lc][(c*2 + ks)*32 + g*8];
#pragma unroll
      for (int nt = 0; nt < 16; ++nt) {
        const int dim = nt*16 + lc;
        int boff = dim*128 + ks*64 + g*16;
        boff ^= (dim & 7) << 4;
        const bf16x8 vb = *(const bf16x8*)((const char*)kv + boff);
        acc[nt] = __builtin_amdgcn_mfma_f32_16x16x32_bf16(pa, vb, acc[nt], 0, 0, 0);
      }
    }
  }

#pragma unroll
  for (int nt = 0; nt < 16; ++nt)
#pragma unroll
    for (int e = 0; e < 4; ++e) {
      const int tok = bT + t0 + wid*16 + g*4 + e;
      y[(size_t)tok * 1024 + h*256 + nt*16 + lc] = f2b(acc[nt][e]);
    }
}

// ---------------- host orchestration ----------------
extern "C" void kernel_launch(void* const* d_in, const int* in_sizes, int n_in,
                              void* d_out, int out_size, void* d_ws, size_t ws_size,
                              hipStream_t stream) {
  const float* x_in      = (const float*)d_in[0];
  const float* ln1_s     = (const float*)d_in[1];
  const float* ln1_b     = (const float*)d_in[2];
  const float* ln2_s     = (const float*)d_in[3];
  const float* ln2_b     = (const float*)d_in[4];
  const float* ln3_s     = (const float*)d_in[5];
  const float* ln3_b     = (const float*)d_in[6];
  const float* rg_in_w   = (const float*)d_in[7];
  const float* rg_in_b   = (const float*)d_in[8];
  const float* rg_gate_w = (const float*)d_in[9];
  const float* rg_gate_b = (const float*)d_in[10];
  const float* rg_out_w  = (const float*)d_in[11];
  const float* rg_out_b  = (const float*)d_in[12];
  const float* qkv_w     = (const float*)d_in[13];
  const float* qkv_b     = (const float*)d_in[14];
  const float* attn_out_w= (const float*)d_in[15];
  const float* attn_out_b= (const float*)d_in[16];
  const float* mlp_w1    = (const float*)d_in[17];
  const float* mlp_b1    = (const float*)d_in[18];
  const float* mlp_w2    = (const float*)d_in[19];
  const float* mlp_b2    = (const float*)d_in[20];

  hipFuncSetAttribute((const void*)&gemm256t<2>, hipFuncAttributeMaxDynamicSharedMemorySize, 73728);
  hipFuncSetAttribute((const void*)&gemm256t<4>, hipFuncAttributeMaxDynamicSharedMemorySize, 73728);
  hipFuncSetAttribute((const void*)&gemm256t<5>, hipFuncAttributeMaxDynamicSharedMemorySize, 73728);
  hipFuncSetAttribute((const void*)&gemm128t<0>, hipFuncAttributeMaxDynamicSharedMemorySize, 49152);
  hipFuncSetAttribute((const void*)&gemm128t<1>, hipFuncAttributeMaxDynamicSharedMemorySize, 49152);

  float* xout = (float*)d_out;
  char* ws = (char*)d_ws;
  u16*  wt     = (u16*)ws;                          // 62,914,560 B (bf16 transposed weights)
  u16*  xn     = (u16*)(ws + 62914560);             // 16,777,216 B
  char* bigS   = ws + 62914560 + 16777216;          // 67,108,864 B
  char* smallS = bigS + 67108864;                   // 16,777,216 B
  float* aggA  = (float*)(smallS + 16777216);
  float* aggB  = aggA + (size_t)BB * NCHUNK * DD;
  float* carry = aggB + (size_t)BB * NCHUNK * DD;
  u16*  xb     = (u16*)(carry + (size_t)BB * NCHUNK * DD);  // 16,777,216 B bf16 residual

  u16* ubuf = (u16*)bigS;                           // RG phase (bf16)
  u16* zbuf = (u16*)(bigS + 33554432);              // pre-sigmoid gate, bf16
  u16* qkb  = (u16*)bigS;                           // attn phase: [8192][2048] QK
  u16* vtb  = (u16*)(bigS + 33554432);              // attn phase: V transposed, 16MB
  u16* hid  = (u16*)bigS;                           // MLP phase
  u16* hbuf = (u16*)smallS;
  u16* ybuf = (u16*)smallS;

  const size_t LW = 15728640;
  const dim3 tb(32, 8);
  // batched over both layers via blockIdx.z
  transpose_cvt<<<dim3(32, 32, 2),  tb, 0, stream>>>(rg_in_w,    wt + 0,        DD, DD,   DD*DD,   LW);
  transpose_cvt<<<dim3(32, 32, 2),  tb, 0, stream>>>(rg_gate_w,  wt + 1048576,  DD, DD,   DD*DD,   LW);
  transpose_cvt<<<dim3(32, 32, 2),  tb, 0, stream>>>(rg_out_w,   wt + 2097152,  DD, DD,   DD*DD,   LW);
  transpose_cvt<<<dim3(96, 32, 2),  tb, 0, stream>>>(qkv_w,      wt + 3145728,  DD, 3072, DD*3072, LW);
  transpose_cvt<<<dim3(32, 32, 2),  tb, 0, stream>>>(attn_out_w, wt + 6291456,  DD, DD,   DD*DD,   LW);
  transpose_cvt<<<dim3(128, 32, 2), tb, 0, stream>>>(mlp_w1,     wt + 7340032,  DD, 4096, DD*4096, LW);
  transpose_cvt<<<dim3(32, 128, 2), tb, 0, stream>>>(mlp_w2,     wt + 11534336, 4096, DD, 4096*DD, LW);

  for (int l = 0; l < NLAYER; ++l) {
    u16* base = wt + (size_t)l * LW;
    // ---- RG-LRU block (rg_in + rg_gate fused; u and pre-sigmoid z stored bf16)
    if (l == 0)
      ln_first_k<<<MM, 256, 0, stream>>>(x_in, ln1_s, ln1_b, xn, xb);
    else
      ln_k<<<MM, 256, 0, stream>>>(xb, ln1_s + l*DD, ln1_b + l*DD, xn);
    gemm256t<5><<<dim3(16, 32), 512, 73728, stream>>>(xn, base + 0, rg_in_b + l*DD, rg_gate_b + l*DD,
                                                      (float*)zbuf, ubuf, DD, 2048);
    scan1_k<<<dim3(4, NCHUNK, BB), 256, 0, stream>>>(zbuf, ubuf, aggA, aggB);
    scan2_k<<<16, 256, 0, stream>>>(aggA, aggB, carry);
    scan3_k<<<dim3(4, NCHUNK, BB), 256, 0, stream>>>(zbuf, ubuf, carry, hbuf);
    gemm128t<0><<<dim3(8, 64), 256, 49152, stream>>>(hbuf, base + 2097152, rg_out_b + l*DD,
                                                     xb, nullptr, xb, DD, 1024);
    // ---- local attention block
    ln_k<<<MM, 256, 0, stream>>>(xb, ln2_s + l*DD, ln2_b + l*DD, xn);
    gemm256t<4><<<dim3(24, 32), 512, 73728, stream>>>(xn, base + 3145728, qkv_b + l*3072, nullptr,
                                                      (float*)vtb, qkb, DD, 3072);
    attn_mfma<<<dim3(TT/64, BB*HH), 256, 0, stream>>>(qkb, vtb, ybuf);
    gemm128t<0><<<dim3(8, 64), 256, 49152, stream>>>(ybuf, base + 6291456, attn_out_b + l*DD,
                                                     xb, nullptr, xb, DD, 1024);
    // ---- MLP block
    ln_k<<<MM, 256, 0, stream>>>(xb, ln3_s + l*DD, ln3_b + l*DD, xn);
    gemm256t<2><<<dim3(32, 32), 512, 73728, stream>>>(xn, base + 7340032, mlp_b1 + l*4096, nullptr,
                                                      nullptr, hid, DD, 4096);
    if (l == NLAYER - 1)
      gemm128t<1><<<dim3(8, 64), 256, 49152, stream>>>(hid, base + 11534336, mlp_b2 + l*DD,
                                                       xb, xout, nullptr, 4096, 1024);
    else
      gemm128t<0><<<dim3(8, 64), 256, 49152, stream>>>(hid, base + 11534336, mlp_b2 + l*DD,
                                                       xb, nullptr, xb, 4096, 1024);
  }
}